// Round 7
// baseline (147.441 us; speedup 1.0000x reference)
//
#include <hip/hip_runtime.h>

typedef unsigned short u16;
typedef _Float16 f16;

#define CIN   64
#define HH    128
#define WW    128
#define NPIX  16384   /* HH*WW */
#define HID   256
#define MTOT  512     /* coef(256) + freq(256) stacked */
#define KTOT  576     /* 64 ch * 9 taps */
#define NB    4
#define WELEM 294912  /* MTOT*KTOT */
#define XROW  130     /* padded input grid row */
#define XROWS 16900   /* 130*130 rows per batch */

/* index-path constants: must bit-match the f32 trace of the reference */
#define SHM  ((float)(-0.0078125 + 1e-6))
#define SHP  ((float)( 0.0078125 + 1e-6))
#define CLO  ((float)(-1.0 + 1e-6))
#define CHI  ((float)( 1.0 - 1e-6))
#define PIF  3.14159265358979323846f

#define QSCL  1024.0f          /* int16 fixed-point scale for YT */
#define QISCL (1.0f / 1024.0f)

using f32x4 = __attribute__((ext_vector_type(4))) float;
using f16x8 = __attribute__((ext_vector_type(8))) _Float16;

/* ---- async global->LDS DMA, 16B per lane (dest = wave base + lane*16) ---- */
typedef __attribute__((address_space(1))) const void gas_void;
typedef __attribute__((address_space(3))) void las_void;
__device__ __forceinline__ void gload16(const void* g, void* l) {
  __builtin_amdgcn_global_load_lds((gas_void*)g, (las_void*)l, 16, 0, 0);
}

/* ---- int16 fixed-point YT helpers ---- */
__device__ __forceinline__ float ldq(const short* p) { return (float)(*p) * QISCL; }
__device__ __forceinline__ void ldqpair(const short* p, float& a, float& b) {
  int u = *(const int*)p;
  a = (float)((short)(u & 0xFFFF)) * QISCL;
  b = (float)((short)(u >> 16)) * QISCL;
}
__device__ __forceinline__ unsigned packq(float a, float b) {
  float fa = fminf(fmaxf(a * QSCL, -32767.f), 32767.f);
  float fb = fminf(fmaxf(b * QSCL, -32767.f), 32767.f);
  int ia = (int)rintf(fa), ib = (int)rintf(fb);
  return ((unsigned)(unsigned short)(short)ia) | (((unsigned)(unsigned short)(short)ib) << 16);
}
/* non-temporal store (single 8B as u64 — builtin requires scalar/ext-vector):
   keep the 67MB YT stream OUT of the per-XCD L2 so the GEMM's A/B working
   sets stay resident (R5 diagnosis: L2 thrash -> L3 BW bound) */
__device__ __forceinline__ void storeq4_nt(short* p, float a, float b, float c, float d) {
  unsigned long long v =
      (unsigned long long)packq(a, b) | ((unsigned long long)packq(c, d) << 32);
  __builtin_nontemporal_store(v, (unsigned long long*)p);
}

/* =====================================================================
 * Kernel 1: repack conv weights -> fp16, pre-tiled per (m-tile, tap) AND
 * pre-XOR-swizzled for bank-conflict-free ds_read after linear DMA:
 * 16B chunk j of row i holds channels (j^(i&7))*8..+8 of tap s.
 * ===================================================================== */
__global__ __launch_bounds__(256) void lte_prep_w(
    const float* __restrict__ cw, const float* __restrict__ fw,
    f16* __restrict__ Awp) {
  int id = blockIdx.x * 256 + threadIdx.x;
  if (id >= WELEM) return;
  int e  = id & 7;
  int j  = (id >> 3) & 7;
  int i  = (id >> 6) & 127;
  int t2 = id >> 13;            /* mt*9 + s */
  int mt = t2 / 9;
  int s  = t2 - mt * 9;
  int ch = ((j ^ (i & 7)) << 3) + e;
  int m  = mt * 128 + i;
  const float* src = (m < HID) ? cw : fw;
  Awp[id] = (f16)src[(m & 255) * KTOT + ch * 9 + s];
}

/* =====================================================================
 * Kernel 1b: input NCHW f32 -> zero-guard-padded pixel-major fp16
 * xp[b][130][130][64]; guard rows/cols zero so GEMM DMA needs no predication.
 * ===================================================================== */
__global__ __launch_bounds__(256) void lte_prep_x(
    const float* __restrict__ inp, f16* __restrict__ xp) {
  int id = blockIdx.x * 256 + threadIdx.x;   /* padded row id, NB*16900 */
  if (id >= NB * XROWS) return;
  int b  = id / XROWS;
  int rr = id - b * XROWS;
  int yy = rr / XROW;
  int x  = rr - yy * XROW - 1;
  int y  = yy - 1;
  f16* op = xp + (size_t)id * 64;
  if ((unsigned)y < 128u && (unsigned)x < 128u) {
    const float* ip = inp + (size_t)b * CIN * NPIX + y * WW + x;
#pragma unroll
    for (int q = 0; q < 8; ++q) {
      f16x8 v;
#pragma unroll
      for (int k = 0; k < 8; ++k) v[k] = (f16)ip[(q * 8 + k) * NPIX];
      *(f16x8*)(op + q * 8) = v;
    }
  } else {
    f16x8 z = {};
#pragma unroll
    for (int q = 0; q < 8; ++q) *(f16x8*)(op + q * 8) = z;
  }
}

/* =====================================================================
 * Kernel 2: implicit-im2col GEMM (m97 structure, validated R5:
 * bank-conflict=0). 1-D grid with XCD-locality swizzle — under
 * round-robin dispatch each XCD gets {all bx} x {2 mt} x {1 bb}, whose
 * A-tiles (2x147KB) + xp slice (2.16MB) fit the 4MB per-XCD L2. YT
 * stores are non-temporal. Output pixel-major int16 YT[b][p][512].
 * ===================================================================== */
__global__ __launch_bounds__(256) void lte_conv_gemm(
    const f16* __restrict__ xp, const f16* __restrict__ Awp,
    const float* __restrict__ coef_b, const float* __restrict__ freq_b,
    short* __restrict__ YT) {
  __shared__ f16 As[128 * 64];   /* 16 KB, [m-row][64 k], linear */
  __shared__ f16 Bs[128 * 64];   /* 16 KB, [pixel][64 ch], linear */

  const int t  = threadIdx.x;
  /* XCD swizzle: wg%8 = XCD (round-robin); give each XCD a contiguous
     256-block span: {all 128 bx} x {2 mt} x {1 bb}. */
  const int wg  = blockIdx.x;
  const int nid = (wg & 7) * 256 + (wg >> 3);
  const int bx  = nid & 127;           /* image row */
  const int mt  = (nid >> 7) & 3;      /* m tile */
  const int bb  = nid >> 9;            /* batch */
  const int l  = t & 63;
  const int w  = t >> 6;
  const int wr = w >> 1, wc = w & 1;
  const int lm = l & 15;
  const int lm7 = lm & 7;
  const int kq = l >> 4;         /* fragment k-chunk 0..3 */
  const int lrow = l >> 3;       /* staging: pixel-in-call 0..7 */
  const int lchk = l & 7;        /* staging: 16B chunk 0..7 */
  const int w8 = w * 8;          /* wave's first staging call */

  f32x4 acc[4][4] = {};

  const f16* Atile = Awp + (size_t)(mt * 9) * 8192;
  const f16* xb = xp + (size_t)bb * XROWS * 64;

#define STAGE(s_)                                                            \
  {                                                                          \
    const int s__ = (s_);                                                    \
    const int ky = s__ / 3, kx = s__ - 3 * (s__ / 3);                        \
    const f16* asrc = Atile + s__ * 8192;                                    \
    const int grow0 = (bx + ky) * XROW + kx;                                 \
    _Pragma("unroll")                                                        \
    for (int i = 0; i < 8; ++i) {                                            \
      const int c = w8 + i;                                                  \
      if (c < 16) {                                                          \
        gload16(asrc + c * 512 + l * 8, As + c * 512);                       \
      } else {                                                               \
        const int cb = c - 16;                                               \
        const int px = cb * 8 + lrow;                                        \
        gload16(xb + (size_t)(grow0 + px) * 64 + ((lchk ^ lrow) << 3),       \
                Bs + cb * 512);                                              \
      }                                                                      \
    }                                                                        \
  }

  STAGE(0)
  __syncthreads();

  for (int s = 0; s < 9; ++s) {
#pragma unroll
    for (int ks = 0; ks < 2; ++ks) {
      const int jl = ks * 4 + kq;            /* logical 16B chunk 0..7 */
      const int pc = (jl ^ lm7) << 3;        /* physical half offset   */
      f16x8 af[4], bg[4];
#pragma unroll
      for (int mi = 0; mi < 4; ++mi)
        af[mi] = *(const f16x8*)&As[(wr * 64 + mi * 16 + lm) * 64 + pc];
#pragma unroll
      for (int ni = 0; ni < 4; ++ni)
        bg[ni] = *(const f16x8*)&Bs[(wc * 64 + ni * 16 + lm) * 64 + pc];
#pragma unroll
      for (int mi = 0; mi < 4; ++mi)
#pragma unroll
        for (int ni = 0; ni < 4; ++ni)
          acc[mi][ni] = __builtin_amdgcn_mfma_f32_16x16x32_f16(af[mi], bg[ni], acc[mi][ni], 0, 0, 0);
    }
    if (s < 8) {
      __syncthreads();          /* all frag reads done before overwrite */
      STAGE(s + 1)
      __syncthreads();          /* staging visible */
    }
  }

  /* epilogue: +bias, quantize, non-temporal store pixel-major YT[b][p][512] */
  const float* bias = (mt < 2) ? (coef_b + mt * 128) : (freq_b + (mt - 2) * 128);
  const int rj = (l >> 4) * 4;
#pragma unroll
  for (int mi = 0; mi < 4; ++mi) {
    const int bm = wr * 64 + mi * 16 + rj;
    const float b0 = bias[bm], b1 = bias[bm + 1], b2 = bias[bm + 2], b3 = bias[bm + 3];
#pragma unroll
    for (int ni = 0; ni < 4; ++ni) {
      const int p = bx * 128 + wc * 64 + ni * 16 + lm;
      size_t off = ((size_t)(bb * NPIX + p)) * 512 + mt * 128 + bm;
      f32x4 v = acc[mi][ni];
      storeq4_nt(&YT[off], v[0] + b0, v[1] + b1, v[2] + b2, v[3] + b3);
    }
  }
}

/* =====================================================================
 * Kernel 3: 4-corner nearest sample + sin/cos modulation (int16 YT).
 * Validated bit-exact index path — unchanged.
 * ===================================================================== */
__global__ __launch_bounds__(128) void lte_sample(
    const short* __restrict__ YT, const float* __restrict__ coord,
    const float* __restrict__ cell, const float* __restrict__ phase_w,
    float* __restrict__ out) {
  __shared__ float lout[256 * 17];
  const int j     = threadIdx.x;          /* 0..127 */
  const int q0    = blockIdx.x * 16;      /* global over B*Q */
  const int b     = q0 >> 14;
  const int q0loc = q0 & (NPIX - 1);
  const float pw0 = phase_w[2 * j], pw1 = phase_w[2 * j + 1];
  const short* Yb = YT + ((size_t)b * NPIX) * 512;

  for (int qi = 0; qi < 16; ++qi) {
    const int qg = q0 + qi;
    const float c0  = coord[2 * qg], c1 = coord[2 * qg + 1];
    const float ce0 = cell[2 * qg],  ce1 = cell[2 * qg + 1];
    const float ph  = (ce0 * 128.0f) * pw0 + (ce1 * 128.0f) * pw1;
    float accC = 0.f, accS = 0.f, tot = 0.f, a3 = 0.f;
#pragma unroll
    for (int ci = 0; ci < 4; ++ci) {     /* (vx,vy): (-,-),(-,+),(+,-),(+,+) */
      const float s0 = (ci & 2) ? SHP : SHM;
      const float s1 = (ci & 1) ? SHP : SHM;
      float cx = fminf(fmaxf(c0 + s0, CLO), CHI);
      float cy = fminf(fmaxf(c1 + s1, CLO), CHI);
      float ty = ((cx + 1.0f) * 128.0f - 1.0f) * 0.5f;
      float tx = ((cy + 1.0f) * 128.0f - 1.0f) * 0.5f;
      float fy = fminf(fmaxf(rintf(ty), 0.f), 127.f);   /* round half-even */
      float fx = fminf(fmaxf(rintf(tx), 0.f), 127.f);
      int iy = (int)fy, ix = (int)fx;
      float qcy = -1.0f + (2.0f * fy + 1.0f) * (1.0f / 128.0f);
      float qcx = -1.0f + (2.0f * fx + 1.0f) * (1.0f / 128.0f);
      float rel0 = (c0 - qcy) * 128.0f;
      float rel1 = (c1 - qcx) * 128.0f;
      float ar = fabsf(rel0 * rel1);
      tot += ar + 1e-9f;
      if (ci == 3) a3 = ar;
      const short* bp = Yb + ((size_t)(iy * 128 + ix)) * 512;
      float coefA = ldq(bp + j);          /* coef channel j    */
      float coefB = ldq(bp + 128 + j);    /* coef channel j+128 */
      float f0, f1;
      ldqpair(bp + 256 + 2 * j, f0, f1);  /* freq pair (2j,2j+1) */
      float f = f0 * rel0 + f1 * rel1 + ph;
      float ang = PIF * f;
      accC += coefA * __cosf(ang);
      accS += coefB * __sinf(ang);
    }
    const float wgt = a3 / tot;
    lout[j * 17 + qi]         = accC * wgt;
    lout[(j + 128) * 17 + qi] = accS * wgt;
  }
  __syncthreads();
#pragma unroll
  for (int pass = 0; pass < 8; ++pass) {
    int c  = pass * 32 + (j >> 2);
    int qf = (j & 3) * 4;
    float4 v;
    v.x = lout[c * 17 + qf];     v.y = lout[c * 17 + qf + 1];
    v.z = lout[c * 17 + qf + 2]; v.w = lout[c * 17 + qf + 3];
    *(float4*)(out + (((size_t)(b * 256 + c)) << 14) + q0loc + qf) = v;
  }
}

extern "C" void kernel_launch(void* const* d_in, const int* in_sizes, int n_in,
                              void* d_out, int out_size, void* d_ws, size_t ws_size,
                              hipStream_t stream) {
  const float* inp     = (const float*)d_in[0];
  const float* coord   = (const float*)d_in[1];
  const float* cell    = (const float*)d_in[2];
  const float* coef_w  = (const float*)d_in[3];
  const float* coef_b  = (const float*)d_in[4];
  const float* freq_w  = (const float*)d_in[5];
  const float* freq_b  = (const float*)d_in[6];
  const float* phase_w = (const float*)d_in[7];
  float* out = (float*)d_out;

  /* ws layout: Awp fp16 (0.59MB) | xp_pad fp16 (8.65MB) | YT int16 (67.1MB). */
  f16* Awp = (f16*)d_ws;
  f16* xp  = (f16*)((char*)d_ws + (size_t)WELEM * 2);
  short* YT = (short*)((char*)d_ws + (size_t)WELEM * 2 + (size_t)NB * XROWS * 64 * 2);

  lte_prep_w<<<dim3(1152), dim3(256), 0, stream>>>(coef_w, freq_w, Awp);
  lte_prep_x<<<dim3((NB * XROWS + 255) / 256), dim3(256), 0, stream>>>(inp, xp);
  lte_conv_gemm<<<dim3(2048), dim3(256), 0, stream>>>(xp, Awp, coef_b, freq_b, YT);
  lte_sample<<<dim3(4096), dim3(128), 0, stream>>>(YT, coord, cell, phase_w, out);
}

// Round 8
// 126.081 us; speedup vs baseline: 1.1694x; 1.1694x over previous
//
#include <hip/hip_runtime.h>

typedef unsigned short u16;
typedef _Float16 f16;

#define CIN   64
#define HH    128
#define WW    128
#define NPIX  16384   /* HH*WW */
#define HID   256
#define MTOT  512     /* coef(256) + freq(256) stacked */
#define KTOT  576     /* 64 ch * 9 taps */
#define NB    4
#define WELEM 294912  /* MTOT*KTOT */
#define XROW  130     /* padded input grid row */
#define XROWS 16900   /* 130*130 rows per batch */

/* index-path constants: must bit-match the f32 trace of the reference */
#define SHM  ((float)(-0.0078125 + 1e-6))
#define SHP  ((float)( 0.0078125 + 1e-6))
#define CLO  ((float)(-1.0 + 1e-6))
#define CHI  ((float)( 1.0 - 1e-6))
#define PIF  3.14159265358979323846f

#define QSCL  1024.0f          /* int16 fixed-point scale for YT */
#define QISCL (1.0f / 1024.0f)

using f32x4 = __attribute__((ext_vector_type(4))) float;
using f16x8 = __attribute__((ext_vector_type(8))) _Float16;

/* ---- async global->LDS DMA, 16B per lane (dest = wave base + lane*16) ---- */
typedef __attribute__((address_space(1))) const void gas_void;
typedef __attribute__((address_space(3))) void las_void;
__device__ __forceinline__ void gload16(const void* g, void* l) {
  __builtin_amdgcn_global_load_lds((gas_void*)g, (las_void*)l, 16, 0, 0);
}

/* ---- int16 fixed-point YT helpers ---- */
__device__ __forceinline__ float ldq(const short* p) { return (float)(*p) * QISCL; }
__device__ __forceinline__ void ldqpair(const short* p, float& a, float& b) {
  int u = *(const int*)p;
  a = (float)((short)(u & 0xFFFF)) * QISCL;
  b = (float)((short)(u >> 16)) * QISCL;
}
__device__ __forceinline__ unsigned packq(float a, float b) {
  float fa = fminf(fmaxf(a * QSCL, -32767.f), 32767.f);
  float fb = fminf(fmaxf(b * QSCL, -32767.f), 32767.f);
  int ia = (int)rintf(fa), ib = (int)rintf(fb);
  return ((unsigned)(unsigned short)(short)ia) | (((unsigned)(unsigned short)(short)ib) << 16);
}
__device__ __forceinline__ void storeq4(short* p, float a, float b, float c, float d) {
  uint2 v; v.x = packq(a, b); v.y = packq(c, d);
  *(uint2*)p = v;
}

/* =====================================================================
 * Kernel 1: repack conv weights -> fp16, pre-tiled per (m-tile, tap) AND
 * pre-XOR-swizzled for bank-conflict-free ds_read after linear DMA:
 * 16B chunk j of row i holds channels (j^(i&7))*8..+8 of tap s.
 * ===================================================================== */
__global__ __launch_bounds__(256) void lte_prep_w(
    const float* __restrict__ cw, const float* __restrict__ fw,
    f16* __restrict__ Awp) {
  int id = blockIdx.x * 256 + threadIdx.x;
  if (id >= WELEM) return;
  int e  = id & 7;
  int j  = (id >> 3) & 7;
  int i  = (id >> 6) & 127;
  int t2 = id >> 13;            /* mt*9 + s */
  int mt = t2 / 9;
  int s  = t2 - mt * 9;
  int ch = ((j ^ (i & 7)) << 3) + e;
  int m  = mt * 128 + i;
  const float* src = (m < HID) ? cw : fw;
  Awp[id] = (f16)src[(m & 255) * KTOT + ch * 9 + s];
}

/* =====================================================================
 * Kernel 1b: input NCHW f32 -> zero-guard-padded pixel-major fp16
 * xp[b][130][130][64]; guard rows/cols zero so GEMM DMA needs no predication.
 * ===================================================================== */
__global__ __launch_bounds__(256) void lte_prep_x(
    const float* __restrict__ inp, f16* __restrict__ xp) {
  int id = blockIdx.x * 256 + threadIdx.x;   /* padded row id, NB*16900 */
  if (id >= NB * XROWS) return;
  int b  = id / XROWS;
  int rr = id - b * XROWS;
  int yy = rr / XROW;
  int x  = rr - yy * XROW - 1;
  int y  = yy - 1;
  f16* op = xp + (size_t)id * 64;
  if ((unsigned)y < 128u && (unsigned)x < 128u) {
    const float* ip = inp + (size_t)b * CIN * NPIX + y * WW + x;
#pragma unroll
    for (int q = 0; q < 8; ++q) {
      f16x8 v;
#pragma unroll
      for (int k = 0; k < 8; ++k) v[k] = (f16)ip[(q * 8 + k) * NPIX];
      *(f16x8*)(op + q * 8) = v;
    }
  } else {
    f16x8 z = {};
#pragma unroll
    for (int q = 0; q < 8; ++q) *(f16x8*)(op + q * 8) = z;
  }
}

/* =====================================================================
 * Kernel 2: implicit-im2col GEMM (bank-conflict-0 DMA staging, validated
 * R5). NEW (T3-minimum pipeline, m248-pattern): LDS double-buffer, issue
 * STAGE(s+1) BEFORE compute(s), single raw s_barrier per K-step with
 * s_waitcnt vmcnt(0) placed AFTER the MFMAs — stage latency hides under
 * compute instead of draining before it. 9 barriers/block (was 18).
 * Output pixel-major int16 YT[b][p][512] (+bias), scale 1024.
 * ===================================================================== */
__global__ __launch_bounds__(256) void lte_conv_gemm(
    const f16* __restrict__ xp, const f16* __restrict__ Awp,
    const float* __restrict__ coef_b, const float* __restrict__ freq_b,
    short* __restrict__ YT) {
  __shared__ f16 As[2][128 * 64];   /* 2 x 16 KB */
  __shared__ f16 Bs[2][128 * 64];   /* 2 x 16 KB */

  const int t  = threadIdx.x;
  const int bx = blockIdx.x;     /* image row y; pixel tile = [bx*128,+128) */
  const int mt = blockIdx.y;     /* m tile (0..3) */
  const int bb = blockIdx.z;     /* batch */
  const int l  = t & 63;
  const int w  = t >> 6;
  const int wr = w >> 1, wc = w & 1;
  const int lm = l & 15;
  const int lm7 = lm & 7;
  const int kq = l >> 4;         /* fragment k-chunk 0..3 */
  const int lrow = l >> 3;       /* staging: pixel-in-call 0..7 */
  const int lchk = l & 7;        /* staging: 16B chunk 0..7 */
  const int w8 = w * 8;          /* wave's first staging call */

  f32x4 acc[4][4] = {};

  const f16* Atile = Awp + (size_t)(mt * 9) * 8192;
  const f16* xb = xp + (size_t)bb * XROWS * 64;

  /* stage tap s into (Ad,Bd): 32 x 1KB DMA calls, 8 per wave.
     A source pre-swizzled linear; B source chunk XOR'd per 128B row. */
  auto stage = [&](int s, f16* Ad, f16* Bd) {
    const int ky = s / 3, kx = s - 3 * (s / 3);
    const f16* asrc = Atile + s * 8192;
    const int grow0 = (bx + ky) * XROW + kx;
#pragma unroll
    for (int i = 0; i < 8; ++i) {
      const int c = w8 + i;
      if (c < 16) {
        gload16(asrc + c * 512 + l * 8, Ad + c * 512);
      } else {
        const int cb = c - 16;
        gload16(xb + (size_t)(grow0 + cb * 8 + lrow) * 64 + ((lchk ^ lrow) << 3),
                Bd + cb * 512);
      }
    }
  };

  stage(0, As[0], Bs[0]);
  asm volatile("s_waitcnt vmcnt(0)" ::: "memory");
  __builtin_amdgcn_s_barrier();
  __builtin_amdgcn_sched_barrier(0);

  for (int s = 0; s < 9; ++s) {
    const int cur = s & 1;
    if (s < 8) stage(s + 1, As[cur ^ 1], Bs[cur ^ 1]);   /* issue-early */
    const f16* Ac = As[cur];
    const f16* Bc = Bs[cur];
#pragma unroll
    for (int ks = 0; ks < 2; ++ks) {
      const int jl = ks * 4 + kq;            /* logical 16B chunk 0..7 */
      const int pc = (jl ^ lm7) << 3;        /* physical half offset   */
      f16x8 af[4], bg[4];
#pragma unroll
      for (int mi = 0; mi < 4; ++mi)
        af[mi] = *(const f16x8*)&Ac[(wr * 64 + mi * 16 + lm) * 64 + pc];
#pragma unroll
      for (int ni = 0; ni < 4; ++ni)
        bg[ni] = *(const f16x8*)&Bc[(wc * 64 + ni * 16 + lm) * 64 + pc];
#pragma unroll
      for (int mi = 0; mi < 4; ++mi)
#pragma unroll
        for (int ni = 0; ni < 4; ++ni)
          acc[mi][ni] = __builtin_amdgcn_mfma_f32_16x16x32_f16(af[mi], bg[ni], acc[mi][ni], 0, 0, 0);
    }
    if (s < 8) {
      /* drain AFTER compute: stage(s+1) latency was hidden under MFMAs */
      asm volatile("s_waitcnt vmcnt(0)" ::: "memory");
      __builtin_amdgcn_s_barrier();
      __builtin_amdgcn_sched_barrier(0);
    }
  }

  /* epilogue: +bias, quantize, store pixel-major YT[b][p][512] */
  const float* bias = (mt < 2) ? (coef_b + mt * 128) : (freq_b + (mt - 2) * 128);
  const int rj = (l >> 4) * 4;
#pragma unroll
  for (int mi = 0; mi < 4; ++mi) {
    const int bm = wr * 64 + mi * 16 + rj;
    const float b0 = bias[bm], b1 = bias[bm + 1], b2 = bias[bm + 2], b3 = bias[bm + 3];
#pragma unroll
    for (int ni = 0; ni < 4; ++ni) {
      const int p = bx * 128 + wc * 64 + ni * 16 + lm;
      size_t off = ((size_t)(bb * NPIX + p)) * 512 + mt * 128 + bm;
      f32x4 v = acc[mi][ni];
      storeq4(&YT[off], v[0] + b0, v[1] + b1, v[2] + b2, v[3] + b3);
    }
  }
}

/* =====================================================================
 * Kernel 3: 4-corner nearest sample + sin/cos modulation (int16 YT).
 * Validated bit-exact index path — unchanged.
 * ===================================================================== */
__global__ __launch_bounds__(128) void lte_sample(
    const short* __restrict__ YT, const float* __restrict__ coord,
    const float* __restrict__ cell, const float* __restrict__ phase_w,
    float* __restrict__ out) {
  __shared__ float lout[256 * 17];
  const int j     = threadIdx.x;          /* 0..127 */
  const int q0    = blockIdx.x * 16;      /* global over B*Q */
  const int b     = q0 >> 14;
  const int q0loc = q0 & (NPIX - 1);
  const float pw0 = phase_w[2 * j], pw1 = phase_w[2 * j + 1];
  const short* Yb = YT + ((size_t)b * NPIX) * 512;

  for (int qi = 0; qi < 16; ++qi) {
    const int qg = q0 + qi;
    const float c0  = coord[2 * qg], c1 = coord[2 * qg + 1];
    const float ce0 = cell[2 * qg],  ce1 = cell[2 * qg + 1];
    const float ph  = (ce0 * 128.0f) * pw0 + (ce1 * 128.0f) * pw1;
    float accC = 0.f, accS = 0.f, tot = 0.f, a3 = 0.f;
#pragma unroll
    for (int ci = 0; ci < 4; ++ci) {     /* (vx,vy): (-,-),(-,+),(+,-),(+,+) */
      const float s0 = (ci & 2) ? SHP : SHM;
      const float s1 = (ci & 1) ? SHP : SHM;
      float cx = fminf(fmaxf(c0 + s0, CLO), CHI);
      float cy = fminf(fmaxf(c1 + s1, CLO), CHI);
      float ty = ((cx + 1.0f) * 128.0f - 1.0f) * 0.5f;
      float tx = ((cy + 1.0f) * 128.0f - 1.0f) * 0.5f;
      float fy = fminf(fmaxf(rintf(ty), 0.f), 127.f);   /* round half-even */
      float fx = fminf(fmaxf(rintf(tx), 0.f), 127.f);
      int iy = (int)fy, ix = (int)fx;
      float qcy = -1.0f + (2.0f * fy + 1.0f) * (1.0f / 128.0f);
      float qcx = -1.0f + (2.0f * fx + 1.0f) * (1.0f / 128.0f);
      float rel0 = (c0 - qcy) * 128.0f;
      float rel1 = (c1 - qcx) * 128.0f;
      float ar = fabsf(rel0 * rel1);
      tot += ar + 1e-9f;
      if (ci == 3) a3 = ar;
      const short* bp = Yb + ((size_t)(iy * 128 + ix)) * 512;
      float coefA = ldq(bp + j);          /* coef channel j    */
      float coefB = ldq(bp + 128 + j);    /* coef channel j+128 */
      float f0, f1;
      ldqpair(bp + 256 + 2 * j, f0, f1);  /* freq pair (2j,2j+1) */
      float f = f0 * rel0 + f1 * rel1 + ph;
      float ang = PIF * f;
      accC += coefA * __cosf(ang);
      accS += coefB * __sinf(ang);
    }
    const float wgt = a3 / tot;
    lout[j * 17 + qi]         = accC * wgt;
    lout[(j + 128) * 17 + qi] = accS * wgt;
  }
  __syncthreads();
#pragma unroll
  for (int pass = 0; pass < 8; ++pass) {
    int c  = pass * 32 + (j >> 2);
    int qf = (j & 3) * 4;
    float4 v;
    v.x = lout[c * 17 + qf];     v.y = lout[c * 17 + qf + 1];
    v.z = lout[c * 17 + qf + 2]; v.w = lout[c * 17 + qf + 3];
    *(float4*)(out + (((size_t)(b * 256 + c)) << 14) + q0loc + qf) = v;
  }
}

extern "C" void kernel_launch(void* const* d_in, const int* in_sizes, int n_in,
                              void* d_out, int out_size, void* d_ws, size_t ws_size,
                              hipStream_t stream) {
  const float* inp     = (const float*)d_in[0];
  const float* coord   = (const float*)d_in[1];
  const float* cell    = (const float*)d_in[2];
  const float* coef_w  = (const float*)d_in[3];
  const float* coef_b  = (const float*)d_in[4];
  const float* freq_w  = (const float*)d_in[5];
  const float* freq_b  = (const float*)d_in[6];
  const float* phase_w = (const float*)d_in[7];
  float* out = (float*)d_out;

  /* ws layout: Awp fp16 (0.59MB) | xp_pad fp16 (8.65MB) | YT int16 (67.1MB). */
  f16* Awp = (f16*)d_ws;
  f16* xp  = (f16*)((char*)d_ws + (size_t)WELEM * 2);
  short* YT = (short*)((char*)d_ws + (size_t)WELEM * 2 + (size_t)NB * XROWS * 64 * 2);

  lte_prep_w<<<dim3(1152), dim3(256), 0, stream>>>(coef_w, freq_w, Awp);
  lte_prep_x<<<dim3((NB * XROWS + 255) / 256), dim3(256), 0, stream>>>(inp, xp);
  lte_conv_gemm<<<dim3(128, 4, 4), dim3(256), 0, stream>>>(xp, Awp, coef_b, freq_b, YT);
  lte_sample<<<dim3(4096), dim3(128), 0, stream>>>(YT, coord, cell, phase_w, out);
}